// Round 9
// baseline (16.862 us; speedup 1.0000x reference)
//
#include <hip/hip_runtime.h>
#include <math.h>

// Geometry (fixed): 256 x 8192 x 3 f32 per input = 2,097,152 rows of 3.
#define N_ROWS   (256 * 8192)
#define BLOCK    256
#define GRID     256                       // persistent: 1 block per CU
#define TILES    8                         // tiles per block
#define F4T      3                         // float4 per thread per input per tile
#define F4B      (BLOCK * F4T)             // 768 float4 = 12 KB per input per tile
// total float4 per input = GRID*TILES*F4B = 256*8*768 = 1,572,864  ✓

// XOR swizzle on float4 index (within 64-float4 groups): conflict-free for
// unit-stride writes; stride-3 reads spread across bank groups (3 coprime 8).
__device__ __forceinline__ int swz(int j) { return j ^ ((j >> 3) & 7); }

// Branchless acos, |err| < 6.8e-5 rad (Abramowitz-Stegun 4.4.45).
__device__ __forceinline__ float acos_fast(float x) {
    float ax = fabsf(x);
    float s  = sqrtf(fmaxf(0.0f, 1.0f - ax));
    float p  = fmaf(ax, -0.0187293f, 0.0742610f);
    p = fmaf(ax, p, -0.2121144f);
    p = fmaf(ax, p, 1.5707288f);
    float r = s * p;
    return (x >= 0.0f) ? r : (3.14159265358979f - r);
}

// 3 float4 (= 4 rows of 3 floats) from each input -> sum of 4 angles.
__device__ __forceinline__ float rows4(float4 a0, float4 a1, float4 a2,
                                       float4 b0, float4 b1, float4 b2) {
    float ox[4] = {a0.x, a0.w, a1.z, a2.y};
    float oy[4] = {a0.y, a1.x, a1.w, a2.z};
    float oz[4] = {a0.z, a1.y, a2.x, a2.w};
    float txv[4] = {b0.x, b0.w, b1.z, b2.y};
    float tyv[4] = {b0.y, b1.x, b1.w, b2.z};
    float tzv[4] = {b0.z, b1.y, b2.x, b2.w};
    float s = 0.0f;
#pragma unroll
    for (int r = 0; r < 4; ++r) {
        float dot = ox[r] * txv[r] + oy[r] * tyv[r] + oz[r] * tzv[r];
        float no2 = ox[r] * ox[r] + oy[r] * oy[r] + oz[r] * oz[r];
        float nt2 = txv[r] * txv[r] + tyv[r] * tyv[r] + tzv[r] * tzv[r];
        float c = dot * rsqrtf(no2) * rsqrtf(nt2);
        c = fminf(1.0f, fmaxf(-1.0f, c));
        s += acos_fast(c);
    }
    return s;
}

__global__ __launch_bounds__(BLOCK) void angle_main(
    const float* __restrict__ o,
    const float* __restrict__ t,
    float* __restrict__ partial)
{
    // Double-buffered tiles: 2 bufs x 2 inputs x 12 KB = 48 KB LDS.
    __shared__ float4 so[2][F4B];
    __shared__ float4 st[2][F4B];

    const int tx  = threadIdx.x;
    const int bid = blockIdx.x;
    const float4* o4 = reinterpret_cast<const float4*>(o);
    const float4* t4 = reinterpret_cast<const float4*>(t);

    // Prologue: tile 0 into registers.
    long gb = (long)(bid * TILES) * F4B;
    float4 ra0 = o4[gb + 0 * BLOCK + tx];
    float4 ra1 = o4[gb + 1 * BLOCK + tx];
    float4 ra2 = o4[gb + 2 * BLOCK + tx];
    float4 rb0 = t4[gb + 0 * BLOCK + tx];
    float4 rb1 = t4[gb + 1 * BLOCK + tx];
    float4 rb2 = t4[gb + 2 * BLOCK + tx];

    float s = 0.0f;
#pragma unroll
    for (int tt = 0; tt < TILES; ++tt) {
        const int p = tt & 1;

        // Write current tile regs -> LDS buf p (vmcnt wait auto-inserted).
        so[p][swz(0 * BLOCK + tx)] = ra0;
        so[p][swz(1 * BLOCK + tx)] = ra1;
        so[p][swz(2 * BLOCK + tx)] = ra2;
        st[p][swz(0 * BLOCK + tx)] = rb0;
        st[p][swz(1 * BLOCK + tx)] = rb1;
        st[p][swz(2 * BLOCK + tx)] = rb2;

        // Issue NEXT tile's 12 global loads; they fly during this tile's
        // barrier + compute, hiding HBM latency.
        if (tt + 1 < TILES) {
            long nb = (long)(bid * TILES + tt + 1) * F4B;
            ra0 = o4[nb + 0 * BLOCK + tx];
            ra1 = o4[nb + 1 * BLOCK + tx];
            ra2 = o4[nb + 2 * BLOCK + tx];
            rb0 = t4[nb + 0 * BLOCK + tx];
            rb1 = t4[nb + 1 * BLOCK + tx];
            rb2 = t4[nb + 2 * BLOCK + tx];
        }

        __syncthreads();
        // One barrier/iter is safe: writes to buf[p] at iter tt+2 cannot
        // start until barrier(tt+1), which no thread passes before all
        // finish compute(tt) on buf[p].

        float4 a0 = so[p][swz(3 * tx + 0)];
        float4 a1 = so[p][swz(3 * tx + 1)];
        float4 a2 = so[p][swz(3 * tx + 2)];
        float4 b0 = st[p][swz(3 * tx + 0)];
        float4 b1 = st[p][swz(3 * tx + 1)];
        float4 b2 = st[p][swz(3 * tx + 2)];

        s += rows4(a0, a1, a2, b0, b1, b2);
    }

    // Wave (64) reduce, then block reduce. No fences/atomics: the kernel
    // boundary is the device-wide sync (rounds 7/8 proved relaxed
    // agent-scope publication is NOT cross-XCD coherent).
#pragma unroll
    for (int off = 32; off > 0; off >>= 1)
        s += __shfl_down(s, off, 64);

    __shared__ float waves[BLOCK / 64];
    const int lane = tx & 63;
    const int wid  = tx >> 6;
    if (lane == 0) waves[wid] = s;
    __syncthreads();

    if (tx == 0) {
        float bs = 0.0f;
#pragma unroll
        for (int w = 0; w < BLOCK / 64; ++w) bs += waves[w];
        partial[bid] = bs;
    }
}

__global__ __launch_bounds__(64) void angle_final(
    const float* __restrict__ partial,
    float* __restrict__ out)
{
    // 256 partials = 64 float4: one vector load per lane, single wave,
    // no LDS, no barrier.
    const float4* p4 = reinterpret_cast<const float4*>(partial);
    float4 v = p4[threadIdx.x];
    float s = v.x + v.y + v.z + v.w;

#pragma unroll
    for (int off = 32; off > 0; off >>= 1)
        s += __shfl_down(s, off, 64);

    if (threadIdx.x == 0)
        out[0] = s / (float)N_ROWS;
}

extern "C" void kernel_launch(void* const* d_in, const int* in_sizes, int n_in,
                              void* d_out, int out_size, void* d_ws, size_t ws_size,
                              hipStream_t stream)
{
    const float* outputs = (const float*)d_in[0];
    const float* targets = (const float*)d_in[1];
    float* out = (float*)d_out;
    float* partial = (float*)d_ws;  // 1 KB scratch

    angle_main<<<GRID, BLOCK, 0, stream>>>(outputs, targets, partial);
    angle_final<<<1, 64, 0, stream>>>(partial, out);
}